// Round 3
// baseline (76.621 us; speedup 1.0000x reference)
//
#include <hip/hip_runtime.h>
#include <math.h>

#define GROUP 8
#define NG 4
#define C2 32
#define CTOT 64
#define L 4096
#define BB 4
#define NSAMP 2048
#define KL 16       // n-stripes per (q,h) group
#define QPB 32      // (b,pos) pairs per block
#define THREADS 1024

typedef float v2f __attribute__((ext_vector_type(2)));

__device__ __forceinline__ v2f pk_fma(v2f a, v2f b, v2f c) {
    v2f d;
    asm("v_pk_fma_f32 %0, %1, %2, %3" : "=v"(d) : "v"(a), "v"(b), "v"(c));
    return d;
}

// Block: 1024 threads = 32 q-groups of 32 lanes.
//   lane bits: k = tid&15 (n-stripe, n = nn*16+k), h = (tid>>4)&1 (ns-pair {2h,2h+1}),
//   q = tid>>5 -> (b,pos).
// Each thread: 2 ns-rows x 128 samples. Grid 512 blocks; LDS 64KB -> 2 blocks/CU
// -> 32 waves/CU (8/SIMD). __launch_bounds__(1024,8) forces VGPR<=64.
//
// score'[r,n] = sum_g (ca*s + cb)*s  with ca = 0.5*(1-iv), cb = mu*iv
// (row-constant rc dropped; -nlp folded into ca; both argmax-invariant).
__global__ __launch_bounds__(THREADS, 8) void gqreg_kernel(
    const float* __restrict__ z, const float* __restrict__ prior,
    float* __restrict__ out /* zhat [B][C2][L] then indices-as-float [B][NG][L] */)
{
    __shared__ float4 s_lo[NSAMP];   // 32 KB: sample n, g=0..3
    __shared__ float4 s_hi[NSAMP];   // 32 KB: sample n, g=4..7

    const int tid = threadIdx.x;

    // ---- stage prior samples into LDS ----
    const float4* p4 = (const float4*)prior;
    #pragma unroll
    for (int i = 0; i < 2; ++i) {
        int n = tid + i * THREADS;
        s_lo[n] = p4[2 * n];
        s_hi[n] = p4[2 * n + 1];
    }

    // ---- per-row coefficients (overlaps staging; no LDS dep) ----
    const int k = tid & (KL - 1);
    const int h = (tid >> 4) & 1;
    const int q = tid >> 5;
    const int Q = blockIdx.x * QPB + q;     // 0 .. B*L-1
    const int b = Q >> 12;
    const int pos = Q & (L - 1);
    const float* zb = z + (size_t)b * CTOT * L + pos;

    v2f ca2[2][4];   // 0.5*(1 - inv_var), packed pairs over g
    v2f cb2[2][4];   // mu * inv_var
    #pragma unroll
    for (int j = 0; j < 2; ++j) {
        int ns = 2 * h + j;
        #pragma unroll
        for (int gp = 0; gp < 4; ++gp) {
            #pragma unroll
            for (int e = 0; e < 2; ++e) {
                int g = gp * 2 + e;
                int ch = g * NG + ns;
                float mu = zb[(size_t)ch * L];
                float lv = zb[(size_t)(C2 + ch) * L];
                lv = fminf(fmaxf(lv, -30.f), 20.f);
                float iv = expf(-lv);
                ca2[j][gp][e] = 0.5f - 0.5f * iv;
                cb2[j][gp][e] = mu * iv;
            }
        }
    }

    __syncthreads();

    // ---- argmax scan ----
    float best[2] = {-INFINITY, -INFINITY};
    int bidx[2] = {0, 0};

    #pragma unroll 2
    for (int nn = 0; nn < NSAMP / KL; ++nn) {
        int n = nn * KL + k;
        float4 u = s_lo[n], v = s_hi[n];
        v2f sp0 = {u.x, u.y}, sp1 = {u.z, u.w}, sp2 = {v.x, v.y}, sp3 = {v.z, v.w};
        #pragma unroll
        for (int j = 0; j < 2; ++j) {
            v2f acc = {0.f, 0.f};
            v2f t;
            t = pk_fma(ca2[j][0], sp0, cb2[j][0]); acc = pk_fma(t, sp0, acc);
            t = pk_fma(ca2[j][1], sp1, cb2[j][1]); acc = pk_fma(t, sp1, acc);
            t = pk_fma(ca2[j][2], sp2, cb2[j][2]); acc = pk_fma(t, sp2, acc);
            t = pk_fma(ca2[j][3], sp3, cb2[j][3]); acc = pk_fma(t, sp3, acc);
            float sc = acc.x + acc.y;
            if (sc > best[j]) { best[j] = sc; bidx[j] = n; }
        }
    }

    // ---- reduce argmax across the 16 k-lanes (tie -> lowest n) ----
    #pragma unroll
    for (int j = 0; j < 2; ++j) {
        #pragma unroll
        for (int m = 1; m < KL; m <<= 1) {
            float os = __shfl_xor(best[j], m, 64);
            int oi = __shfl_xor(bidx[j], m, 64);
            if (os > best[j] || (os == best[j] && oi < bidx[j])) {
                best[j] = os; bidx[j] = oi;
            }
        }
    }

    // ---- write outputs (lane k==0 of each (q,h) group writes its 2 ns-rows) ----
    if (k == 0) {
        float* zout = out + (size_t)b * C2 * L + pos;
        float* iout = out + (size_t)BB * C2 * L + (size_t)b * NG * L + pos;
        #pragma unroll
        for (int j = 0; j < 2; ++j) {
            int ns = 2 * h + j;
            int n = bidx[j];
            iout[(size_t)ns * L] = (float)n;
            float4 u = s_lo[n], v = s_hi[n];
            float sv[GROUP] = {u.x, u.y, u.z, u.w, v.x, v.y, v.z, v.w};
            #pragma unroll
            for (int g = 0; g < GROUP; ++g) {
                zout[(size_t)(g * NG + ns) * L] = sv[g];
            }
        }
    }
}

extern "C" void kernel_launch(void* const* d_in, const int* in_sizes, int n_in,
                              void* d_out, int out_size, void* d_ws, size_t ws_size,
                              hipStream_t stream) {
    const float* z = (const float*)d_in[0];
    const float* prior = (const float*)d_in[1];
    float* out = (float*)d_out;
    dim3 grid((BB * L) / QPB);
    dim3 block(THREADS);
    hipLaunchKernelGGL(gqreg_kernel, grid, block, 0, stream, z, prior, out);
}

// Round 4
// 65.068 us; speedup vs baseline: 1.1776x; 1.1776x over previous
//
#include <hip/hip_runtime.h>
#include <math.h>

#define GROUP 8
#define NG 4
#define C2 32
#define CTOT 64
#define L 4096
#define BB 4
#define NSAMP 2048
#define TILE 1024   // samples staged per pass (32 KB)
#define KL 16       // n-stripes per q
#define QPB 32      // (b,pos) pairs per block
#define THREADS 512

// Block: 512 threads. tid>>4 = q (0..31) -> (b,pos); tid&15 = k -> n-stripe.
// Each thread owns the 4 ns-rows of its (b,pos) (best LDS amortization:
// 32B LDS read serves 64 FMA). Samples staged in TWO 1024-sample tiles so
// LDS/block = 32KB -> 4 blocks/CU -> 32 waves/CU (8/SIMD), vs 2 blocks at 64KB.
//
// score'[r,n] = sum_g (ca*s + cb)*s, ca = 0.5*(1-iv), cb = mu*iv
// (row-constant rc dropped, -nlp folded into ca: both argmax-invariant).
__global__ __launch_bounds__(THREADS) void gqreg_kernel(
    const float* __restrict__ z, const float* __restrict__ prior,
    float* __restrict__ out /* zhat [B][C2][L] then indices-as-float [B][NG][L] */)
{
    __shared__ float4 s_lo[TILE];   // 16 KB: sample n, g=0..3
    __shared__ float4 s_hi[TILE];   // 16 KB: sample n, g=4..7

    const int tid = threadIdx.x;
    const float4* p4 = (const float4*)prior;

    // ---- stage tile 0 (overlaps coeff computation below) ----
    #pragma unroll
    for (int i = 0; i < 2; ++i) {
        int n = tid + i * THREADS;
        s_lo[n] = p4[2 * n];
        s_hi[n] = p4[2 * n + 1];
    }

    // ---- per-row coefficients ----
    const int k = tid & (KL - 1);
    const int q = tid >> 4;
    const int Q = blockIdx.x * QPB + q;     // 0 .. B*L-1
    const int b = Q >> 12;
    const int pos = Q & (L - 1);
    const float* zb = z + (size_t)b * CTOT * L + pos;

    float ca[NG][GROUP];   // 0.5*(1 - inv_var)
    float cb[NG][GROUP];   // mu * inv_var
    #pragma unroll
    for (int ns = 0; ns < NG; ++ns) {
        #pragma unroll
        for (int g = 0; g < GROUP; ++g) {
            int ch = g * NG + ns;
            float mu = zb[(size_t)ch * L];
            float lv = zb[(size_t)(C2 + ch) * L];
            lv = fminf(fmaxf(lv, -30.f), 20.f);
            float iv = expf(-lv);
            ca[ns][g] = 0.5f - 0.5f * iv;
            cb[ns][g] = mu * iv;
        }
    }

    float best[NG] = {-INFINITY, -INFINITY, -INFINITY, -INFINITY};
    int bidx[NG] = {0, 0, 0, 0};

    #pragma unroll
    for (int t = 0; t < NSAMP / TILE; ++t) {
        if (t > 0) {
            __syncthreads();   // scan of previous tile done; safe to overwrite
            #pragma unroll
            for (int i = 0; i < 2; ++i) {
                int nl = tid + i * THREADS;
                int n = t * TILE + nl;
                s_lo[nl] = p4[2 * n];
                s_hi[nl] = p4[2 * n + 1];
            }
        }
        __syncthreads();

        #pragma unroll 4
        for (int nn = 0; nn < TILE / KL; ++nn) {
            int nl = nn * KL + k;
            int n = t * TILE + nl;
            float4 u = s_lo[nl], v = s_hi[nl];
            float s[GROUP] = {u.x, u.y, u.z, u.w, v.x, v.y, v.z, v.w};
            #pragma unroll
            for (int ns = 0; ns < NG; ++ns) {
                float acc = 0.f;
                #pragma unroll
                for (int g = 0; g < GROUP; ++g) {
                    float tt = fmaf(ca[ns][g], s[g], cb[ns][g]);
                    acc = fmaf(tt, s[g], acc);
                }
                if (acc > best[ns]) { best[ns] = acc; bidx[ns] = n; }
            }
        }
    }

    // ---- reduce argmax across the 16 stripe lanes (tie -> lowest n) ----
    #pragma unroll
    for (int ns = 0; ns < NG; ++ns) {
        #pragma unroll
        for (int m = 1; m < KL; m <<= 1) {
            float os = __shfl_xor(best[ns], m, 64);
            int oi = __shfl_xor(bidx[ns], m, 64);
            if (os > best[ns] || (os == best[ns] && oi < bidx[ns])) {
                best[ns] = os; bidx[ns] = oi;
            }
        }
    }

    // ---- write outputs (lane k==0); gather zhat from global prior (L2-hot),
    //      since LDS tile 0 has been overwritten ----
    if (k == 0) {
        float* zout = out + (size_t)b * C2 * L + pos;
        float* iout = out + (size_t)BB * C2 * L + (size_t)b * NG * L + pos;
        #pragma unroll
        for (int ns = 0; ns < NG; ++ns) {
            int n = bidx[ns];
            iout[(size_t)ns * L] = (float)n;
            float4 u = p4[2 * n], v = p4[2 * n + 1];
            float sv[GROUP] = {u.x, u.y, u.z, u.w, v.x, v.y, v.z, v.w};
            #pragma unroll
            for (int g = 0; g < GROUP; ++g) {
                zout[(size_t)(g * NG + ns) * L] = sv[g];
            }
        }
    }
}

extern "C" void kernel_launch(void* const* d_in, const int* in_sizes, int n_in,
                              void* d_out, int out_size, void* d_ws, size_t ws_size,
                              hipStream_t stream) {
    const float* z = (const float*)d_in[0];
    const float* prior = (const float*)d_in[1];
    float* out = (float*)d_out;
    dim3 grid((BB * L) / QPB);
    dim3 block(THREADS);
    hipLaunchKernelGGL(gqreg_kernel, grid, block, 0, stream, z, prior, out);
}